// Round 4
// baseline (187.760 us; speedup 1.0000x reference)
//
#include <hip/hip_runtime.h>
#include <math.h>

// CRF log-likelihood, B=2048, T=80, L=128 — v4: barrier-free, LDS-free MFMA
// forward. One wave (64 thr) per 16 batch rows; all 128 states per wave.
// A = permuted E^T entirely in registers (8 m-tiles x 4 k-frags).
// State permutation g makes the MFMA C-layout output pack DIRECTLY into the
// next step's B-fragments (register renaming only): g((a<<4)|(q<<2)|r) =
// ((a>>1)<<5)|(q<<3)|((a&1)<<2)|r. A absorbs g^-1; x/start/end unpermuted.
// Renorm every 4 steps, delayed one step (growth <= ~1.3e19, fp32/bf16 safe).

#define CRF_B 2048
#define CRF_T 80
#define CRF_L 128

typedef __attribute__((ext_vector_type(8))) short bf16x8_t;
typedef __attribute__((ext_vector_type(4))) float f32x4_t;

union bfrag { bf16x8_t v; unsigned u[4]; unsigned short s[8]; };

__device__ __forceinline__ unsigned pack2(float lo, float hi) {
    // two positive fp32 -> packed bf16x2 (truncation)
    return (__float_as_uint(lo) >> 16) | (__float_as_uint(hi) & 0xFFFF0000u);
}
__device__ __forceinline__ unsigned short bft(float f) {
    return (unsigned short)(__float_as_uint(f) >> 16);
}

__global__ __launch_bounds__(64, 1) void crf_v4_kernel(
    const float* __restrict__ x,           // [B,T,L]
    const float* __restrict__ trans,       // [L,L]
    const float* __restrict__ start_trans, // [L]
    const float* __restrict__ end_trans,   // [L]
    const int*   __restrict__ y,           // [B,T]
    float* __restrict__ out)               // [B]
{
    const int lane = threadIdx.x;   // 0..63
    const int q    = lane >> 4;     // quad
    const int n16  = lane & 15;     // batch row within tile
    const int row0 = blockIdx.x * 16;
    const int brow = row0 + n16;

    const float* xr = x + (size_t)brow * (CRF_T * CRF_L);

    // ---------------- numerator: 4 lanes (quads) per row ----------------
    const int* yb = y + brow * CRF_T;
    float nume = 0.f;
    #pragma unroll
    for (int i = 0; i < 20; ++i) {
        const int t  = 4 * i + q;
        const int yt = yb[t];
        nume += xr[t * CRF_L + yt];
        nume += (t < CRF_T - 1) ? trans[yt * CRF_L + yb[t + 1]] : end_trans[yt];
        if (t == 0) nume += start_trans[yt];
    }
    nume += __shfl_xor(nume, 16);
    nume += __shfl_xor(nume, 32);   // all lanes: numerator for row n16

    // -------- A-frags: A'[m][v] = exp(trans[g^-1(v)][m]), registers only --------
    // lane(q,n16), tile mt, frag kk, elem j: m = 16mt+n16, v = 32kk+8q+j,
    // g^-1(v) = ((2kk + (j>>2))<<4) | (q<<2) | (j&3)
    bfrag Af[8][4];
    #pragma unroll
    for (int mt = 0; mt < 8; ++mt) {
        const int m = 16 * mt + n16;
        #pragma unroll
        for (int kk = 0; kk < 4; ++kk) {
            #pragma unroll
            for (int j = 0; j < 8; ++j) {
                const int s = ((2 * kk + (j >> 2)) << 4) | (q << 2) | (j & 3);
                Af[mt][kk].s[j] = bft(__expf(trans[s * CRF_L + m]));
            }
        }
    }

    // x double buffers (2-step prefetch distance)
    f32x4_t xA[8], xB[8];
    #pragma unroll
    for (int mt = 0; mt < 8; ++mt) {
        xA[mt] = *(const f32x4_t*)&xr[0 * CRF_L + 16 * mt + 4 * q];
        xB[mt] = *(const f32x4_t*)&xr[1 * CRF_L + 16 * mt + 4 * q];
    }

    bfrag   Bf[4];
    f32x4_t acc[8];
    float crun = 0.f, invM = 1.f;

    // ---------------- step 0 ----------------
    #pragma unroll
    for (int mt = 0; mt < 8; ++mt) {
        const f32x4_t st4 = *(const f32x4_t*)&start_trans[16 * mt + 4 * q];
        #pragma unroll
        for (int r = 0; r < 4; ++r)
            acc[mt][r] = __expf(st4[r] + xA[mt][r]);
    }
    #pragma unroll
    for (int mt = 0; mt < 8; ++mt) {
        Bf[mt >> 1].u[2 * (mt & 1) + 0] = pack2(acc[mt][0], acc[mt][1]);
        Bf[mt >> 1].u[2 * (mt & 1) + 1] = pack2(acc[mt][2], acc[mt][3]);
    }
    #pragma unroll
    for (int mt = 0; mt < 8; ++mt)
        xA[mt] = *(const f32x4_t*)&xr[2 * CRF_L + 16 * mt + 4 * q];

    // ---------------- generic step ----------------
    auto step = [&](int t, f32x4_t (&xc)[8]) {
        #pragma unroll
        for (int mt = 0; mt < 8; ++mt) {
            f32x4_t a = {0.f, 0.f, 0.f, 0.f};
            #pragma unroll
            for (int kk = 0; kk < 4; ++kk)
                a = __builtin_amdgcn_mfma_f32_16x16x32_bf16(Af[mt][kk].v, Bf[kk].v, a, 0, 0, 0);
            acc[mt] = a;
        }
        const bool ap = (t & 3) == 0;   // apply invM pending from renorm at t-1
        #pragma unroll
        for (int mt = 0; mt < 8; ++mt) {
            #pragma unroll
            for (int r = 0; r < 4; ++r) {
                float e = __expf(xc[mt][r]);
                if (ap) e *= invM;
                acc[mt][r] *= e;
            }
        }
        if (((t & 3) == 3) && (t < CRF_T - 1)) {
            float m = acc[0][0];
            #pragma unroll
            for (int mt = 0; mt < 8; ++mt)
                #pragma unroll
                for (int r = 0; r < 4; ++r)
                    m = fmaxf(m, acc[mt][r]);
            m = fmaxf(m, __shfl_xor(m, 16));
            m = fmaxf(m, __shfl_xor(m, 32));
            crun += __logf(m);          // per-row, uniform across quads
            invM  = 1.0f / m;
        }
        if (t < CRF_T - 1) {
            #pragma unroll
            for (int mt = 0; mt < 8; ++mt) {
                Bf[mt >> 1].u[2 * (mt & 1) + 0] = pack2(acc[mt][0], acc[mt][1]);
                Bf[mt >> 1].u[2 * (mt & 1) + 1] = pack2(acc[mt][2], acc[mt][3]);
            }
        }
        if (t + 2 < CRF_T) {
            #pragma unroll
            for (int mt = 0; mt < 8; ++mt)
                xc[mt] = *(const f32x4_t*)&xr[(t + 2) * CRF_L + 16 * mt + 4 * q];
        }
    };

    for (int tb = 1; tb + 1 < CRF_T; tb += 2) {  // steps 1..78
        step(tb,     xB);
        step(tb + 1, xA);
    }
    step(CRF_T - 1, xB);                          // t = 79 (odd): no pack/renorm

    // ---------------- epilogue ----------------
    float sv = 0.f;
    #pragma unroll
    for (int mt = 0; mt < 8; ++mt) {
        const f32x4_t e4 = *(const f32x4_t*)&end_trans[16 * mt + 4 * q];
        #pragma unroll
        for (int r = 0; r < 4; ++r)
            sv += acc[mt][r] * __expf(e4[r]);
    }
    sv += __shfl_xor(sv, 16);
    sv += __shfl_xor(sv, 32);
    if (lane < 16) out[row0 + n16] = nume - (crun + __logf(sv));
}

extern "C" void kernel_launch(void* const* d_in, const int* in_sizes, int n_in,
                              void* d_out, int out_size, void* d_ws, size_t ws_size,
                              hipStream_t stream) {
    const float* x     = (const float*)d_in[0];
    const float* trans = (const float*)d_in[1];
    const float* st    = (const float*)d_in[2];
    const float* et    = (const float*)d_in[3];
    const int*   y     = (const int*)d_in[4];
    float* out = (float*)d_out;

    crf_v4_kernel<<<CRF_B / 16, 64, 0, stream>>>(x, trans, st, et, y, out);
}